// Round 6
// baseline (410.921 us; speedup 1.0000x reference)
//
#include <hip/hip_runtime.h>
#include <hip/hip_bf16.h>

// MHA forward, S=2048 B=2 D=1024 H=16 DK=64.
// R9: attn_kernel de-barriered (R8 counters: MfmaUtil 9.4%, VALUBusy 24%,
// occupancy 21%, everything idle -> latency/barrier-bound; 32 barriers/block
// around tiny compute chunks). K-tile (16KB/head) is L1/L2-resident across the
// 4 waves and 32 s-blocks sharing it -> LDS staging was pure overhead (guide
// common-mistake #7). attn now: NO LDS, NO barriers, per-lane global b128 K
// frag loads, fully independent waves. em (h-independent) hoisted out of the
// h-loop: acc += exp2(C)*rl_h, final *= em/16 (saves 32 VALU/head/lane).
// flash (R8 swapped-QK^T register-P), proj/outproj (m97 GEMM), cvt unchanged.
// MFMA 16x16x32 bf16 layouts (guide-verified):
//   A-frag: A[m=lane&15][k=quad*8+j], B-frag: B[k=quad*8+j][n=lane&15],
//   C/D:    D[row=quad*4+reg][col=lane&15].
// Outputs are FLOAT32 — d_out = float*.

#define S_LEN 2048
#define BATCH 2
#define DMODEL 1024
#define NH 16
#define DKH 64
#define SCALE 0.125f   // 1/sqrt(64)
#define QSCALE 0.180336878f  // SCALE * log2(e), folded into q at proj time
#define FMAX 20.0f     // fixed softmax offset (scores max ~9, no overflow)
#define KSTRIDE 72     // padded LDS row stride (144B, 16B-aligned)

typedef __bf16 bf16_t;
typedef __attribute__((ext_vector_type(8))) __bf16 bf16x8;
typedef __attribute__((ext_vector_type(8))) unsigned short u16x8;
typedef __attribute__((ext_vector_type(4))) unsigned short u16x4;
typedef __attribute__((ext_vector_type(4))) float f32x4;

__device__ __forceinline__ unsigned short f32_bf16_rne(float f) {
  union { float f; unsigned int u; } v; v.f = f;
  unsigned int u = v.u;
  u += 0x7fffu + ((u >> 16) & 1u);
  return (unsigned short)(u >> 16);
}
__device__ __forceinline__ float bf16u_f32(unsigned short us) {
  union { unsigned int u; float f; } v; v.u = ((unsigned int)us) << 16;
  return v.f;
}
__device__ __forceinline__ f32x4 mfma_bf16(bf16x8 a, bf16x8 b, f32x4 c) {
  return __builtin_amdgcn_mfma_f32_16x16x32_bf16(a, b, c, 0, 0, 0);
}
__device__ __forceinline__ float exp2_fast(float x) {
#if __has_builtin(__builtin_amdgcn_exp2f)
  return __builtin_amdgcn_exp2f(x);   // v_exp_f32 (2^x) directly
#else
  return __expf(x * 0.69314718f);
#endif
}
__device__ __forceinline__ unsigned int cvtpk(float lo, float hi) {
  unsigned int r;
  asm("v_cvt_pk_bf16_f32 %0, %1, %2" : "=v"(r) : "v"(lo), "v"(hi));
  return r;
}
// async global->LDS, 16B per lane. LDS dest is wave-uniform base + lane*16.
__device__ __forceinline__ void gload16(const bf16_t* g, unsigned short* l) {
  __builtin_amdgcn_global_load_lds(
      (const __attribute__((address_space(1))) void*)g,
      (__attribute__((address_space(3))) void*)l, 16, 0, 0);
}

// ---------------- kernel 1a: four (D,D) weights -> bf16 --------------------
__global__ __launch_bounds__(256) void cvt_w_kernel(
    const float* __restrict__ w0, const float* __restrict__ w1,
    const float* __restrict__ w2, const float* __restrict__ w3,
    bf16_t* __restrict__ o0, bf16_t* __restrict__ o1,
    bf16_t* __restrict__ o2, bf16_t* __restrict__ o3) {
  const float* src; bf16_t* dst;
  switch (blockIdx.y) {
    case 0: src = w0; dst = o0; break;
    case 1: src = w1; dst = o1; break;
    case 2: src = w2; dst = o2; break;
    default: src = w3; dst = o3; break;
  }
  int i = (blockIdx.x * 256 + threadIdx.x) * 4;
  float4 v = *(const float4*)(src + i);
  union { unsigned short u[4]; uint2 q; } r;
  r.u[0] = f32_bf16_rne(v.x); r.u[1] = f32_bf16_rne(v.y);
  r.u[2] = f32_bf16_rne(v.z); r.u[3] = f32_bf16_rne(v.w);
  *(uint2*)(dst + i) = r.q;
}

// ---------------- kernel 1b: three (S,B,D) inputs -> bf16 ------------------
__global__ __launch_bounds__(256) void cvt_x_kernel(
    const float* __restrict__ x0, const float* __restrict__ x1,
    const float* __restrict__ x2,
    bf16_t* __restrict__ o0, bf16_t* __restrict__ o1, bf16_t* __restrict__ o2) {
  const float* src; bf16_t* dst;
  switch (blockIdx.y) {
    case 0: src = x0; dst = o0; break;
    case 1: src = x1; dst = o1; break;
    default: src = x2; dst = o2; break;
  }
  int i = (blockIdx.x * 256 + threadIdx.x) * 4;
  float4 v = *(const float4*)(src + i);
  union { unsigned short u[4]; uint2 q; } r;
  r.u[0] = f32_bf16_rne(v.x); r.u[1] = f32_bf16_rne(v.y);
  r.u[2] = f32_bf16_rne(v.z); r.u[3] = f32_bf16_rne(v.w);
  *(uint2*)(dst + i) = r.q;
}

// ---------------- kernel 1c: mask (B,S,S) -> em = exp(m - FMAX) bf16 -------
__global__ __launch_bounds__(256) void cvt_mask_kernel(
    const float* __restrict__ m, bf16_t* __restrict__ o) {
  int i = (blockIdx.x * 256 + threadIdx.x) * 4;
  float4 v = *(const float4*)(m + i);
  union { unsigned short u[4]; uint2 q; } r;
  r.u[0] = f32_bf16_rne(__expf(v.x - FMAX));
  r.u[1] = f32_bf16_rne(__expf(v.y - FMAX));
  r.u[2] = f32_bf16_rne(__expf(v.z - FMAX));
  r.u[3] = f32_bf16_rne(__expf(v.w - FMAX));
  *(uint2*)(o + i) = r.q;
}

// ---------------- kernel 2: q/k/v projections (m97-structure GEMM) ---------
// grid (M/128=32, N/128=8, 3 modes), 256 thr = 4 waves (2x2), wave owns 64x64.
// mode 0 (q) output pre-scaled by QSCALE (q only feeds QK^T -> exp2 path).
__global__ __launch_bounds__(256) void proj_kernel(
    const bf16_t* __restrict__ Xq, const bf16_t* __restrict__ Xk, const bf16_t* __restrict__ Xv,
    const bf16_t* __restrict__ Wqb, const bf16_t* __restrict__ Wkb, const bf16_t* __restrict__ Wvb,
    const float* __restrict__ bq, const float* __restrict__ bk, const float* __restrict__ bv,
    bf16_t* __restrict__ qo, bf16_t* __restrict__ ko, bf16_t* __restrict__ vTo) {
  int mode = blockIdx.z;
  const bf16_t* X = (mode == 0) ? Xq : (mode == 1) ? Xk : Xv;
  const bf16_t* W = (mode == 0) ? Wqb : (mode == 1) ? Wkb : Wvb;
  const float* bias = (mode == 0) ? bq : (mode == 1) ? bk : bv;

  __shared__ __align__(16) unsigned short Alds[128 * 32];  // 8 KB
  __shared__ __align__(16) unsigned short Blds[128 * 32];  // 8 KB

  int tid = threadIdx.x;
  int wv = tid >> 6, lane = tid & 63, quad = lane >> 4, col = lane & 15;
  int wr = wv >> 1, wc = wv & 1;
  int rowbase = blockIdx.x * 128;
  int colbase = blockIdx.y * 128;

  int srow = tid >> 2;           // 0..63
  int sk8 = (tid & 3) * 8;       // k-elem offset of the chunk
  const bf16_t* ga0 = X + (size_t)(rowbase + srow) * DMODEL + sk8;
  const bf16_t* gb0 = W + (size_t)(colbase + srow) * DMODEL + sk8;
  unsigned short* la0 = Alds + tid * 8;     // byte offset tid*16 (linear)
  unsigned short* lb0 = Blds + tid * 8;

  f32x4 acc[4][4] = {};

  for (int k0 = 0; k0 < DMODEL; k0 += 32) {
    gload16(ga0 + k0, la0);
    gload16(ga0 + 64 * DMODEL + k0, la0 + 2048);
    gload16(gb0 + k0, lb0);
    gload16(gb0 + 64 * DMODEL + k0, lb0 + 2048);
    __syncthreads();

    union { u16x8 u; bf16x8 v; } af[4], bfr[4];
#pragma unroll
    for (int mi = 0; mi < 4; ++mi)
      af[mi].u = *(const u16x8*)(Alds + (wr * 64 + mi * 16 + col) * 32 + quad * 8);
#pragma unroll
    for (int ni = 0; ni < 4; ++ni)
      bfr[ni].u = *(const u16x8*)(Blds + (wc * 64 + ni * 16 + col) * 32 + quad * 8);
#pragma unroll
    for (int mi = 0; mi < 4; ++mi)
#pragma unroll
      for (int ni = 0; ni < 4; ++ni)
        acc[mi][ni] = mfma_bf16(af[mi].v, bfr[ni].v, acc[mi][ni]);
    __syncthreads();
  }

  float biasv[4];
#pragma unroll
  for (int ni = 0; ni < 4; ++ni)
    biasv[ni] = bias[colbase + wc * 64 + ni * 16 + col];

#pragma unroll
  for (int mi = 0; mi < 4; ++mi)
#pragma unroll
    for (int ni = 0; ni < 4; ++ni)
#pragma unroll
      for (int r = 0; r < 4; ++r) {
        int grow = rowbase + wr * 64 + mi * 16 + quad * 4 + r;
        int gcol = colbase + wc * 64 + ni * 16 + col;
        float val = acc[mi][ni][r] + biasv[ni];
        if (mode == 0) val *= QSCALE;
        unsigned short us = f32_bf16_rne(val);
        int s = grow >> 1, bb = grow & 1;
        int h = gcol >> 6, dk = gcol & 63;
        if (mode == 2) {
          ((unsigned short*)vTo)[((size_t)(bb * NH + h) * DKH + dk) * S_LEN + s] = us;
        } else {
          unsigned short* dst = (unsigned short*)(mode == 0 ? qo : ko);
          dst[((size_t)(bb * NH + h) * S_LEN + s) * DKH + dk] = us;
        }
      }
}

// ---------------- kernel 3: flash (swapped QK^T, register P) ---------------
// grid 512 linear: xcd=bid&7 owns 4 bh; 256 thr = 4 waves; wave owns 32 q-rows
// (2 sets of 16). K staged pi-permuted so p lands in PV B-frag order.
// pi(pos) = (pos&32) + ((pos&16)>>2) + ((pos&12)<<1) + (pos&3).
__global__ __launch_bounds__(256) void flash_kernel(
    const bf16_t* __restrict__ emb,
    const bf16_t* __restrict__ q_ws, const bf16_t* __restrict__ k_ws,
    const bf16_t* __restrict__ vT_ws,
    bf16_t* __restrict__ x_ws, float* __restrict__ rl_ws) {
  int tid = threadIdx.x;
  int w = tid >> 6, lane = tid & 63, quad = lane >> 4, col = lane & 15;

  int bid = blockIdx.x;
  int wi = bid >> 3;
  int bh = (bid & 7) * 4 + (wi & 3);   // XCD-bijective: xcd owns bh group
  int qblk = wi >> 2;                   // 0..15
  int b = bh >> 4;                      // NH = 16
  int s0 = qblk * 128 + w * 32;
  int sA = s0, sB = s0 + 16;

  __shared__ __align__(16) unsigned short Klds[64 * KSTRIDE];  // 9 KB (pi-permuted rows)
  __shared__ __align__(16) unsigned short Vlds[64 * KSTRIDE];  // 9 KB

  const bf16_t* qh = q_ws + (size_t)bh * S_LEN * DKH;
  const bf16_t* kh = k_ws + (size_t)bh * S_LEN * DKH;
  const bf16_t* vh = vT_ws + (size_t)bh * DKH * S_LEN;
  const unsigned short* emA = (const unsigned short*)emb +
      (size_t)b * S_LEN * S_LEN + (size_t)(sA + col) * S_LEN;
  const unsigned short* emB = emA + (size_t)16 * S_LEN;

  // Q frags (B-operand layout == row-read): Q[sX+col][quad*8.. / 32+quad*8..]
  bf16x8 qA0 = *(const bf16x8*)(qh + (sA + col) * DKH + quad * 8);
  bf16x8 qA1 = *(const bf16x8*)(qh + (sA + col) * DKH + 32 + quad * 8);
  bf16x8 qB0 = *(const bf16x8*)(qh + (sB + col) * DKH + quad * 8);
  bf16x8 qB1 = *(const bf16x8*)(qh + (sB + col) * DKH + 32 + quad * 8);

  // staging: thread covers LDS rows row1 (0..31) and row2=row1+32, chunk ch
  int row1 = tid >> 3, row2 = row1 + 32;
  int ch = (tid & 7) * 8;
  int pi1 = (row1 & 32) + ((row1 & 16) >> 2) + ((row1 & 12) << 1) + (row1 & 3);
  int pi2 = (row2 & 32) + ((row2 & 16) >> 2) + ((row2 & 12) << 1) + (row2 & 3);
  const unsigned short* kg1 = (const unsigned short*)kh + (size_t)pi1 * DKH + ch;
  const unsigned short* kg2 = (const unsigned short*)kh + (size_t)pi2 * DKH + ch;
  const unsigned short* vg1 = (const unsigned short*)vh + (size_t)row1 * S_LEN + ch;
  const unsigned short* vg2 = (const unsigned short*)vh + (size_t)row2 * S_LEN + ch;
  u16x8* kl1 = (u16x8*)(Klds + row1 * KSTRIDE + ch);
  u16x8* kl2 = (u16x8*)(Klds + row2 * KSTRIDE + ch);
  u16x8* vl1 = (u16x8*)(Vlds + row1 * KSTRIDE + ch);
  u16x8* vl2 = (u16x8*)(Vlds + row2 * KSTRIDE + ch);

  f32x4 xA[4] = {}, xB[4] = {};
  float lsumA = 0.0f, lsumB = 0.0f;

  u16x8 kp1 = *(const u16x8*)kg1;   // t0 = 0 prefetch (pi baked into address)
  u16x8 kp2 = *(const u16x8*)kg2;
  u16x8 vp1 = *(const u16x8*)vg1;
  u16x8 vp2 = *(const u16x8*)vg2;

  for (int t0 = 0; t0 < S_LEN; t0 += 64) {
    *kl1 = kp1; *kl2 = kp2; *vl1 = vp1; *vl2 = vp2;
    __syncthreads();

    // prefetch next tile (T14: latency hides under compute)
    if (t0 + 64 < S_LEN) {
      kp1 = *(const u16x8*)(kg1 + (size_t)(t0 + 64) * DKH);
      kp2 = *(const u16x8*)(kg2 + (size_t)(t0 + 64) * DKH);
      vp1 = *(const u16x8*)(vg1 + (t0 + 64));
      vp2 = *(const u16x8*)(vg2 + (t0 + 64));
    }

    // em (value-domain mask), vectorized u16x4 at permuted t offsets
    u16x4 emA4[4], emB4[4];
#pragma unroll
    for (int j = 0; j < 4; ++j) {
      int f = t0 + ((j >> 1) << 5) + ((j & 1) << 2) + quad * 8;
      emA4[j] = *(const u16x4*)(emA + f);
      emB4[j] = *(const u16x4*)(emB + f);
    }

    // ---- swapped QK^T: C = K . Q^T -> lane holds P^T[t][q=col] ----
    f32x4 CA[4], CB[4];
#pragma unroll
    for (int j = 0; j < 4; ++j) {
      union { u16x8 u; bf16x8 v; } kb0, kb1;
      int row = j * 16 + col;
      kb0.u = *(const u16x8*)(Klds + row * KSTRIDE + quad * 8);
      kb1.u = *(const u16x8*)(Klds + row * KSTRIDE + 32 + quad * 8);
      f32x4 z = {};
      CA[j] = mfma_bf16(kb1.v, qA1, mfma_bf16(kb0.v, qA0, z));
      CB[j] = mfma_bf16(kb1.v, qB1, mfma_bf16(kb0.v, qB0, z));
    }

    // ---- softmax numerators: p = exp2(C)*em; pack straight into B-frags ----
    unsigned int PA[8], PB[8];
#pragma unroll
    for (int j = 0; j < 4; ++j) {
      float a0 = exp2_fast(CA[j][0]) * bf16u_f32(emA4[j][0]);
      float a1 = exp2_fast(CA[j][1]) * bf16u_f32(emA4[j][1]);
      float a2 = exp2_fast(CA[j][2]) * bf16u_f32(emA4[j][2]);
      float a3 = exp2_fast(CA[j][3]) * bf16u_f32(emA4[j][3]);
      lsumA += (a0 + a1) + (a2 + a3);
      PA[j * 2] = cvtpk(a0, a1);
      PA[j * 2 + 1] = cvtpk(a2, a3);
      float b0 = exp2_fast(CB[j][0]) * bf16u_f32(emB4[j][0]);
      float b1 = exp2_fast(CB[j][1]) * bf16u_f32(emB4[j][1]);
      float b2 = exp2_fast(CB[j][2]) * bf16u_f32(emB4[j][2]);
      float b3 = exp2_fast(CB[j][3]) * bf16u_f32(emB4[j][3]);
      lsumB += (b0 + b1) + (b2 + b3);
      PB[j * 2] = cvtpk(b0, b1);
      PB[j * 2 + 1] = cvtpk(b2, b3);
    }
    union { unsigned int u32[4]; bf16x8 v; } bA0, bA1, bB0, bB1;
#pragma unroll
    for (int i = 0; i < 4; ++i) {
      bA0.u32[i] = PA[i]; bA1.u32[i] = PA[4 + i];
      bB0.u32[i] = PB[i]; bB1.u32[i] = PB[4 + i];
    }

    // ---- PV: X^T = V^T . P^T (V frags shared by both q-sets) ----
#pragma unroll
    for (int ni = 0; ni < 4; ++ni) {
      union { u16x8 u; bf16x8 v; } vb0, vb1;
      int row = ni * 16 + col;
      vb0.u = *(const u16x8*)(Vlds + row * KSTRIDE + quad * 8);
      vb1.u = *(const u16x8*)(Vlds + row * KSTRIDE + 32 + quad * 8);
      xA[ni] = mfma_bf16(vb1.v, bA1.v, mfma_bf16(vb0.v, bA0.v, xA[ni]));
      xB[ni] = mfma_bf16(vb1.v, bB1.v, mfma_bf16(vb0.v, bB0.v, xB[ni]));
    }
    __syncthreads();
  }

  // denominators: sum over quads (lanes col, col+16, col+32, col+48)
  lsumA += __shfl_xor(lsumA, 16, 64); lsumA += __shfl_xor(lsumA, 32, 64);
  lsumB += __shfl_xor(lsumB, 16, 64); lsumB += __shfl_xor(lsumB, 32, 64);
  float rlA = 1.0f / lsumA, rlB = 1.0f / lsumB;

  // X^T[d = ni*16+quad*4+r][q = sX+col] -> x_ws[bh][q][d], 8B stores
  unsigned short* xo = (unsigned short*)x_ws;
#pragma unroll
  for (int ni = 0; ni < 4; ++ni) {
    uint2 wa, wb;
    wa.x = cvtpk(xA[ni][0] * rlA, xA[ni][1] * rlA);
    wa.y = cvtpk(xA[ni][2] * rlA, xA[ni][3] * rlA);
    wb.x = cvtpk(xB[ni][0] * rlB, xB[ni][1] * rlB);
    wb.y = cvtpk(xB[ni][2] * rlB, xB[ni][3] * rlB);
    *(uint2*)(xo + ((size_t)bh * S_LEN + sA + col) * DKH + ni * 16 + quad * 4) = wa;
    *(uint2*)(xo + ((size_t)bh * S_LEN + sB + col) * DKH + ni * 16 + quad * 4) = wb;
  }
  if (quad == 0) {
    rl_ws[(size_t)bh * S_LEN + sA + col] = rlA;
    rl_ws[(size_t)bh * S_LEN + sB + col] = rlB;
  }
}

// ---------------- kernel 4: attn = mean_h softmax (no LDS, no barriers) ----
// grid (S/64=32, B, S/128=16); 256 thr = 4 waves, fully independent.
// Per head: direct per-lane global b128 K frag loads (K tile is L1/L2-hot
// across waves and s-blocks), 16 MFMA, exp2+fma. em factored out of h-loop.
__global__ __launch_bounds__(256) void attn_kernel(
    const bf16_t* __restrict__ emb,
    const bf16_t* __restrict__ q_ws, const bf16_t* __restrict__ k_ws,
    const float* __restrict__ rl_ws,
    float* __restrict__ attn_out) {
  int tid = threadIdx.x;
  int w = tid >> 6, lane = tid & 63, quad = lane >> 4, col = lane & 15;
  int b = blockIdx.y;
  int s0 = blockIdx.x * 64 + w * 16;
  int t_base = blockIdx.z * 128;

  const unsigned short* emrow = (const unsigned short*)emb +
      (size_t)b * S_LEN * S_LEN + (size_t)(s0 + quad * 4) * S_LEN + t_base;
  float emf[8][4];
#pragma unroll
  for (int j = 0; j < 8; ++j)
#pragma unroll
    for (int r = 0; r < 4; ++r)
      emf[j][r] = bf16u_f32(emrow[r * S_LEN + j * 16 + col]);

  f32x4 acc[8] = {};

  const bf16_t* qh0 = q_ws + (size_t)(b * NH) * S_LEN * DKH + (size_t)(s0 + col) * DKH;
  const bf16_t* kh0 = k_ws + (size_t)(b * NH) * S_LEN * DKH + (size_t)(t_base + col) * DKH;
  const float* rlp = rl_ws + (size_t)(b * NH) * S_LEN + s0 + quad * 4;

  for (int h = 0; h < NH; ++h) {
    const bf16_t* qp = qh0 + (size_t)h * S_LEN * DKH;
    bf16x8 qf0 = *(const bf16x8*)(qp + quad * 8);
    bf16x8 qf1 = *(const bf16x8*)(qp + 32 + quad * 8);
    const float* rlh = rlp + (size_t)h * S_LEN;
    float rl4[4];
#pragma unroll
    for (int r = 0; r < 4; ++r) rl4[r] = rlh[r];

    const bf16_t* kt = kh0 + (size_t)h * S_LEN * DKH;
#pragma unroll
    for (int j = 0; j < 8; ++j) {
      const bf16_t* kr = kt + (size_t)(j * 16) * DKH;
      bf16x8 kb0 = *(const bf16x8*)(kr + quad * 8);
      bf16x8 kb1 = *(const bf16x8*)(kr + 32 + quad * 8);
      f32x4 z = {};
      f32x4 C = mfma_bf16(qf1, kb1, mfma_bf16(qf0, kb0, z));
#pragma unroll
      for (int r = 0; r < 4; ++r)
        acc[j][r] = fmaf(exp2_fast(C[r]), rl4[r], acc[j][r]);
    }
  }

#pragma unroll
  for (int j = 0; j < 8; ++j)
#pragma unroll
    for (int r = 0; r < 4; ++r)
      attn_out[((size_t)b * S_LEN + s0 + quad * 4 + r) * S_LEN + t_base + j * 16 + col] =
          acc[j][r] * emf[j][r] * (1.0f / NH);
}

// ---------------- kernel 5: out projection (m97-structure GEMM, f32 out) ---
// grid (M/128=32, N/128=8); 256 thr = 4 waves (2x2), wave owns 64x64.
__global__ __launch_bounds__(256) void outproj_kernel(
    const bf16_t* __restrict__ x_ws, const bf16_t* __restrict__ Wob,
    const float* __restrict__ bo, float* __restrict__ out) {
  __shared__ __align__(16) unsigned short Alds[128 * 32];  // 8 KB
  __shared__ __align__(16) unsigned short Blds[128 * 32];  // 8 KB

  int tid = threadIdx.x;
  int wv = tid >> 6, lane = tid & 63, quad = lane >> 4, col = lane & 15;
  int wr = wv >> 1, wc = wv & 1;
  int rowbase = blockIdx.x * 128;
  int colbase = blockIdx.y * 128;

  int srow = tid >> 2;           // 0..63
  int sk8 = (tid & 3) * 8;       // k-elem offset of the chunk
  int r0 = rowbase + srow;       // A rows for staging (and r0+64)
  int s0a = r0 >> 1, b0a = r0 & 1;
  int r1 = r0 + 64;
  int s1a = r1 >> 1, b1a = r1 & 1;
  const bf16_t* gb0 = Wob + (size_t)(colbase + srow) * DMODEL + sk8;
  unsigned short* la0 = Alds + tid * 8;
  unsigned short* lb0 = Blds + tid * 8;

  f32x4 acc[4][4] = {};

  for (int k0 = 0; k0 < DMODEL; k0 += 32) {
    int h = k0 >> 6, dk = (k0 & 63) + sk8;  // head-scattered A source
    gload16(x_ws + ((size_t)(b0a * NH + h) * S_LEN + s0a) * DKH + dk, la0);
    gload16(x_ws + ((size_t)(b1a * NH + h) * S_LEN + s1a) * DKH + dk, la0 + 2048);
    gload16(gb0 + k0, lb0);
    gload16(gb0 + 64 * DMODEL + k0, lb0 + 2048);
    __syncthreads();

    union { u16x8 u; bf16x8 v; } af[4], bfr[4];
#pragma unroll
    for (int mi = 0; mi < 4; ++mi)
      af[mi].u = *(const u16x8*)(Alds + (wr * 64 + mi * 16 + col) * 32 + quad * 8);
#pragma unroll
    for (int ni = 0; ni < 4; ++ni)
      bfr[ni].u = *(const u16x8*)(Blds + (wc * 64 + ni * 16 + col) * 32 + quad * 8);
#pragma unroll
    for (int mi = 0; mi < 4; ++mi)
#pragma unroll
      for (int ni = 0; ni < 4; ++ni)
        acc[mi][ni] = mfma_bf16(af[mi].v, bfr[ni].v, acc[mi][ni]);
    __syncthreads();
  }

  float biasv[4];
#pragma unroll
  for (int ni = 0; ni < 4; ++ni)
    biasv[ni] = bo[colbase + wc * 64 + ni * 16 + col];

#pragma unroll
  for (int mi = 0; mi < 4; ++mi)
#pragma unroll
    for (int ni = 0; ni < 4; ++ni)
#pragma unroll
      for (int r = 0; r < 4; ++r) {
        int grow = rowbase + wr * 64 + mi * 16 + quad * 4 + r;  // == s*B + b
        int gcol = colbase + wc * 64 + ni * 16 + col;
        out[(size_t)grow * DMODEL + gcol] = acc[mi][ni][r] + biasv[ni];
      }
}

// ---------------- launch ----------------------------------------------------
extern "C" void kernel_launch(void* const* d_in, const int* in_sizes, int n_in,
                              void* d_out, int out_size, void* d_ws, size_t ws_size,
                              hipStream_t stream) {
  const float* query = (const float*)d_in[0];
  const float* key_  = (const float*)d_in[1];
  const float* value = (const float*)d_in[2];
  const float* mask  = (const float*)d_in[3];
  const float* Wq = (const float*)d_in[4];
  const float* bq = (const float*)d_in[5];
  const float* Wk = (const float*)d_in[6];
  const float* bk = (const float*)d_in[7];
  const float* Wv = (const float*)d_in[8];
  const float* bv = (const float*)d_in[9];
  const float* Wo = (const float*)d_in[10];
  const float* bo = (const float*)d_in[11];

  char* ws = (char*)d_ws;
  bf16_t* q_ws  = (bf16_t*)(ws + 0);          //  8 MB (B,H,S,DK), pre-scaled
  bf16_t* k_ws  = (bf16_t*)(ws + 8388608);    //  8 MB (B,H,S,DK)
  bf16_t* vT_ws = (bf16_t*)(ws + 16777216);   //  8 MB (B,H,DK,S)
  bf16_t* x_ws  = (bf16_t*)(ws + 25165824);   //  8 MB; aliases Xq-bf16 during proj
  float*  rl_ws = (float*)(ws + 33554432);    //  256 KB (B,H,S)
  bf16_t* Wqb = (bf16_t*)(ws + 33816576);     //  2 MB each
  bf16_t* Wkb = (bf16_t*)(ws + 35913728);
  bf16_t* Wvb = (bf16_t*)(ws + 38010880);
  bf16_t* Wob = (bf16_t*)(ws + 40108032);
  bf16_t* Xq_b = x_ws;                        //  8 MB (consumed by proj)
  bf16_t* Xk_b = (bf16_t*)(ws + 42205184);    //  8 MB (consumed by proj)
  bf16_t* Xv_b = (bf16_t*)(ws + 50593792);    //  8 MB (consumed by proj)
  bf16_t* emb  = (bf16_t*)(ws + 42205184);    // 16.8 MB; overwrites Xk_b/Xv_b AFTER proj

  float* outp  = (float*)d_out;                              // (S,B,D) f32
  float* attnp = outp + (size_t)S_LEN * BATCH * DMODEL;      // (B,S,S) f32

  cvt_w_kernel<<<dim3(1024, 4), 256, 0, stream>>>(Wq, Wk, Wv, Wo, Wqb, Wkb, Wvb, Wob);
  cvt_x_kernel<<<dim3(4096, 3), 256, 0, stream>>>(query, key_, value, Xq_b, Xk_b, Xv_b);
  proj_kernel<<<dim3(32, 8, 3), 256, 0, stream>>>(Xq_b, Xk_b, Xv_b,
                                                  Wqb, Wkb, Wvb, bq, bk, bv,
                                                  q_ws, k_ws, vT_ws);
  cvt_mask_kernel<<<dim3(8192), 256, 0, stream>>>(mask, emb);
  flash_kernel<<<dim3(512), 256, 0, stream>>>(emb, q_ws, k_ws, vT_ws, x_ws, rl_ws);
  attn_kernel<<<dim3(32, 2, 16), 256, 0, stream>>>(emb, q_ws, k_ws, rl_ws, attnp);
  outproj_kernel<<<dim3(32, 8), 256, 0, stream>>>(x_ws, Wob, bo, outp);
}

// Round 8
// 307.529 us; speedup vs baseline: 1.3362x; 1.3362x over previous
//
#include <hip/hip_runtime.h>
#include <hip/hip_bf16.h>

// MHA forward, S=2048 B=2 D=1024 H=16 DK=64.
// R10 (resubmit; prior run died in container acquisition, no verdict):
// attn rebuilt (R9's no-LDS attn regressed 70->142us: killed cross-wave
// K sharing + MLP collapsed, HBM 1191->561 GB/s). Now: 8-wave blocks (128 q),
// K double-buffered in LDS via global_load_lds (stage h+1 before compute h,
// ONE barrier/head), source-side XOR swizzle (rule #21: gload_lds dest must be
// linear -> swizzle the global src chunk, read with same XOR) -> conflict-free
// unpadded [128][64] tile. q/rl prefetched to regs (T14). em-hoist kept (R9,
// verified): acc += exp2(C)*rl_h, final *= em/16.
// flash (R8 swapped-QK^T register-P), proj/outproj (m97 GEMM), cvt unchanged.
// MFMA 16x16x32 bf16 layouts (guide-verified):
//   A-frag: A[m=lane&15][k=quad*8+j], B-frag: B[k=quad*8+j][n=lane&15],
//   C/D:    D[row=quad*4+reg][col=lane&15].
// Outputs are FLOAT32 — d_out = float*.

#define S_LEN 2048
#define BATCH 2
#define DMODEL 1024
#define NH 16
#define DKH 64
#define SCALE 0.125f   // 1/sqrt(64)
#define QSCALE 0.180336878f  // SCALE * log2(e), folded into q at proj time
#define FMAX 20.0f     // fixed softmax offset (scores max ~9, no overflow)
#define KSTRIDE 72     // padded LDS row stride for flash (144B, 16B-aligned)

typedef __bf16 bf16_t;
typedef __attribute__((ext_vector_type(8))) __bf16 bf16x8;
typedef __attribute__((ext_vector_type(8))) unsigned short u16x8;
typedef __attribute__((ext_vector_type(4))) unsigned short u16x4;
typedef __attribute__((ext_vector_type(4))) float f32x4;

__device__ __forceinline__ unsigned short f32_bf16_rne(float f) {
  union { float f; unsigned int u; } v; v.f = f;
  unsigned int u = v.u;
  u += 0x7fffu + ((u >> 16) & 1u);
  return (unsigned short)(u >> 16);
}
__device__ __forceinline__ float bf16u_f32(unsigned short us) {
  union { unsigned int u; float f; } v; v.u = ((unsigned int)us) << 16;
  return v.f;
}
__device__ __forceinline__ f32x4 mfma_bf16(bf16x8 a, bf16x8 b, f32x4 c) {
  return __builtin_amdgcn_mfma_f32_16x16x32_bf16(a, b, c, 0, 0, 0);
}
__device__ __forceinline__ float exp2_fast(float x) {
#if __has_builtin(__builtin_amdgcn_exp2f)
  return __builtin_amdgcn_exp2f(x);   // v_exp_f32 (2^x) directly
#else
  return __expf(x * 0.69314718f);
#endif
}
__device__ __forceinline__ unsigned int cvtpk(float lo, float hi) {
  unsigned int r;
  asm("v_cvt_pk_bf16_f32 %0, %1, %2" : "=v"(r) : "v"(lo), "v"(hi));
  return r;
}
// async global->LDS, 16B per lane. LDS dest is wave-uniform base + lane*16.
__device__ __forceinline__ void gload16(const bf16_t* g, unsigned short* l) {
  __builtin_amdgcn_global_load_lds(
      (const __attribute__((address_space(1))) void*)g,
      (__attribute__((address_space(3))) void*)l, 16, 0, 0);
}

// ---------------- kernel 1a: four (D,D) weights -> bf16 --------------------
__global__ __launch_bounds__(256) void cvt_w_kernel(
    const float* __restrict__ w0, const float* __restrict__ w1,
    const float* __restrict__ w2, const float* __restrict__ w3,
    bf16_t* __restrict__ o0, bf16_t* __restrict__ o1,
    bf16_t* __restrict__ o2, bf16_t* __restrict__ o3) {
  const float* src; bf16_t* dst;
  switch (blockIdx.y) {
    case 0: src = w0; dst = o0; break;
    case 1: src = w1; dst = o1; break;
    case 2: src = w2; dst = o2; break;
    default: src = w3; dst = o3; break;
  }
  int i = (blockIdx.x * 256 + threadIdx.x) * 4;
  float4 v = *(const float4*)(src + i);
  union { unsigned short u[4]; uint2 q; } r;
  r.u[0] = f32_bf16_rne(v.x); r.u[1] = f32_bf16_rne(v.y);
  r.u[2] = f32_bf16_rne(v.z); r.u[3] = f32_bf16_rne(v.w);
  *(uint2*)(dst + i) = r.q;
}

// ---------------- kernel 1b: three (S,B,D) inputs -> bf16 ------------------
__global__ __launch_bounds__(256) void cvt_x_kernel(
    const float* __restrict__ x0, const float* __restrict__ x1,
    const float* __restrict__ x2,
    bf16_t* __restrict__ o0, bf16_t* __restrict__ o1, bf16_t* __restrict__ o2) {
  const float* src; bf16_t* dst;
  switch (blockIdx.y) {
    case 0: src = x0; dst = o0; break;
    case 1: src = x1; dst = o1; break;
    default: src = x2; dst = o2; break;
  }
  int i = (blockIdx.x * 256 + threadIdx.x) * 4;
  float4 v = *(const float4*)(src + i);
  union { unsigned short u[4]; uint2 q; } r;
  r.u[0] = f32_bf16_rne(v.x); r.u[1] = f32_bf16_rne(v.y);
  r.u[2] = f32_bf16_rne(v.z); r.u[3] = f32_bf16_rne(v.w);
  *(uint2*)(dst + i) = r.q;
}

// ---------------- kernel 1c: mask (B,S,S) -> em = exp(m - FMAX) bf16 -------
__global__ __launch_bounds__(256) void cvt_mask_kernel(
    const float* __restrict__ m, bf16_t* __restrict__ o) {
  int i = (blockIdx.x * 256 + threadIdx.x) * 4;
  float4 v = *(const float4*)(m + i);
  union { unsigned short u[4]; uint2 q; } r;
  r.u[0] = f32_bf16_rne(__expf(v.x - FMAX));
  r.u[1] = f32_bf16_rne(__expf(v.y - FMAX));
  r.u[2] = f32_bf16_rne(__expf(v.z - FMAX));
  r.u[3] = f32_bf16_rne(__expf(v.w - FMAX));
  *(uint2*)(o + i) = r.q;
}

// ---------------- kernel 2: q/k/v projections (m97-structure GEMM) ---------
// grid (M/128=32, N/128=8, 3 modes), 256 thr = 4 waves (2x2), wave owns 64x64.
// mode 0 (q) output pre-scaled by QSCALE (q only feeds QK^T -> exp2 path).
__global__ __launch_bounds__(256) void proj_kernel(
    const bf16_t* __restrict__ Xq, const bf16_t* __restrict__ Xk, const bf16_t* __restrict__ Xv,
    const bf16_t* __restrict__ Wqb, const bf16_t* __restrict__ Wkb, const bf16_t* __restrict__ Wvb,
    const float* __restrict__ bq, const float* __restrict__ bk, const float* __restrict__ bv,
    bf16_t* __restrict__ qo, bf16_t* __restrict__ ko, bf16_t* __restrict__ vTo) {
  int mode = blockIdx.z;
  const bf16_t* X = (mode == 0) ? Xq : (mode == 1) ? Xk : Xv;
  const bf16_t* W = (mode == 0) ? Wqb : (mode == 1) ? Wkb : Wvb;
  const float* bias = (mode == 0) ? bq : (mode == 1) ? bk : bv;

  __shared__ __align__(16) unsigned short Alds[128 * 32];  // 8 KB
  __shared__ __align__(16) unsigned short Blds[128 * 32];  // 8 KB

  int tid = threadIdx.x;
  int wv = tid >> 6, lane = tid & 63, quad = lane >> 4, col = lane & 15;
  int wr = wv >> 1, wc = wv & 1;
  int rowbase = blockIdx.x * 128;
  int colbase = blockIdx.y * 128;

  int srow = tid >> 2;           // 0..63
  int sk8 = (tid & 3) * 8;       // k-elem offset of the chunk
  const bf16_t* ga0 = X + (size_t)(rowbase + srow) * DMODEL + sk8;
  const bf16_t* gb0 = W + (size_t)(colbase + srow) * DMODEL + sk8;
  unsigned short* la0 = Alds + tid * 8;     // byte offset tid*16 (linear)
  unsigned short* lb0 = Blds + tid * 8;

  f32x4 acc[4][4] = {};

  for (int k0 = 0; k0 < DMODEL; k0 += 32) {
    gload16(ga0 + k0, la0);
    gload16(ga0 + 64 * DMODEL + k0, la0 + 2048);
    gload16(gb0 + k0, lb0);
    gload16(gb0 + 64 * DMODEL + k0, lb0 + 2048);
    __syncthreads();

    union { u16x8 u; bf16x8 v; } af[4], bfr[4];
#pragma unroll
    for (int mi = 0; mi < 4; ++mi)
      af[mi].u = *(const u16x8*)(Alds + (wr * 64 + mi * 16 + col) * 32 + quad * 8);
#pragma unroll
    for (int ni = 0; ni < 4; ++ni)
      bfr[ni].u = *(const u16x8*)(Blds + (wc * 64 + ni * 16 + col) * 32 + quad * 8);
#pragma unroll
    for (int mi = 0; mi < 4; ++mi)
#pragma unroll
      for (int ni = 0; ni < 4; ++ni)
        acc[mi][ni] = mfma_bf16(af[mi].v, bfr[ni].v, acc[mi][ni]);
    __syncthreads();
  }

  float biasv[4];
#pragma unroll
  for (int ni = 0; ni < 4; ++ni)
    biasv[ni] = bias[colbase + wc * 64 + ni * 16 + col];

#pragma unroll
  for (int mi = 0; mi < 4; ++mi)
#pragma unroll
    for (int ni = 0; ni < 4; ++ni)
#pragma unroll
      for (int r = 0; r < 4; ++r) {
        int grow = rowbase + wr * 64 + mi * 16 + quad * 4 + r;
        int gcol = colbase + wc * 64 + ni * 16 + col;
        float val = acc[mi][ni][r] + biasv[ni];
        if (mode == 0) val *= QSCALE;
        unsigned short us = f32_bf16_rne(val);
        int s = grow >> 1, bb = grow & 1;
        int h = gcol >> 6, dk = gcol & 63;
        if (mode == 2) {
          ((unsigned short*)vTo)[((size_t)(bb * NH + h) * DKH + dk) * S_LEN + s] = us;
        } else {
          unsigned short* dst = (unsigned short*)(mode == 0 ? qo : ko);
          dst[((size_t)(bb * NH + h) * S_LEN + s) * DKH + dk] = us;
        }
      }
}

// ---------------- kernel 3: flash (swapped QK^T, register P) ---------------
// grid 512 linear: xcd=bid&7 owns 4 bh; 256 thr = 4 waves; wave owns 32 q-rows
// (2 sets of 16). K staged pi-permuted so p lands in PV B-frag order.
// pi(pos) = (pos&32) + ((pos&16)>>2) + ((pos&12)<<1) + (pos&3).
__global__ __launch_bounds__(256) void flash_kernel(
    const bf16_t* __restrict__ emb,
    const bf16_t* __restrict__ q_ws, const bf16_t* __restrict__ k_ws,
    const bf16_t* __restrict__ vT_ws,
    bf16_t* __restrict__ x_ws, float* __restrict__ rl_ws) {
  int tid = threadIdx.x;
  int w = tid >> 6, lane = tid & 63, quad = lane >> 4, col = lane & 15;

  int bid = blockIdx.x;
  int wi = bid >> 3;
  int bh = (bid & 7) * 4 + (wi & 3);   // XCD-bijective: xcd owns bh group
  int qblk = wi >> 2;                   // 0..15
  int b = bh >> 4;                      // NH = 16
  int s0 = qblk * 128 + w * 32;
  int sA = s0, sB = s0 + 16;

  __shared__ __align__(16) unsigned short Klds[64 * KSTRIDE];  // 9 KB (pi-permuted rows)
  __shared__ __align__(16) unsigned short Vlds[64 * KSTRIDE];  // 9 KB

  const bf16_t* qh = q_ws + (size_t)bh * S_LEN * DKH;
  const bf16_t* kh = k_ws + (size_t)bh * S_LEN * DKH;
  const bf16_t* vh = vT_ws + (size_t)bh * DKH * S_LEN;
  const unsigned short* emA = (const unsigned short*)emb +
      (size_t)b * S_LEN * S_LEN + (size_t)(sA + col) * S_LEN;
  const unsigned short* emB = emA + (size_t)16 * S_LEN;

  // Q frags (B-operand layout == row-read): Q[sX+col][quad*8.. / 32+quad*8..]
  bf16x8 qA0 = *(const bf16x8*)(qh + (sA + col) * DKH + quad * 8);
  bf16x8 qA1 = *(const bf16x8*)(qh + (sA + col) * DKH + 32 + quad * 8);
  bf16x8 qB0 = *(const bf16x8*)(qh + (sB + col) * DKH + quad * 8);
  bf16x8 qB1 = *(const bf16x8*)(qh + (sB + col) * DKH + 32 + quad * 8);

  // staging: thread covers LDS rows row1 (0..31) and row2=row1+32, chunk ch
  int row1 = tid >> 3, row2 = row1 + 32;
  int ch = (tid & 7) * 8;
  int pi1 = (row1 & 32) + ((row1 & 16) >> 2) + ((row1 & 12) << 1) + (row1 & 3);
  int pi2 = (row2 & 32) + ((row2 & 16) >> 2) + ((row2 & 12) << 1) + (row2 & 3);
  const unsigned short* kg1 = (const unsigned short*)kh + (size_t)pi1 * DKH + ch;
  const unsigned short* kg2 = (const unsigned short*)kh + (size_t)pi2 * DKH + ch;
  const unsigned short* vg1 = (const unsigned short*)vh + (size_t)row1 * S_LEN + ch;
  const unsigned short* vg2 = (const unsigned short*)vh + (size_t)row2 * S_LEN + ch;
  u16x8* kl1 = (u16x8*)(Klds + row1 * KSTRIDE + ch);
  u16x8* kl2 = (u16x8*)(Klds + row2 * KSTRIDE + ch);
  u16x8* vl1 = (u16x8*)(Vlds + row1 * KSTRIDE + ch);
  u16x8* vl2 = (u16x8*)(Vlds + row2 * KSTRIDE + ch);

  f32x4 xA[4] = {}, xB[4] = {};
  float lsumA = 0.0f, lsumB = 0.0f;

  u16x8 kp1 = *(const u16x8*)kg1;   // t0 = 0 prefetch (pi baked into address)
  u16x8 kp2 = *(const u16x8*)kg2;
  u16x8 vp1 = *(const u16x8*)vg1;
  u16x8 vp2 = *(const u16x8*)vg2;

  for (int t0 = 0; t0 < S_LEN; t0 += 64) {
    *kl1 = kp1; *kl2 = kp2; *vl1 = vp1; *vl2 = vp2;
    __syncthreads();

    // prefetch next tile (T14: latency hides under compute)
    if (t0 + 64 < S_LEN) {
      kp1 = *(const u16x8*)(kg1 + (size_t)(t0 + 64) * DKH);
      kp2 = *(const u16x8*)(kg2 + (size_t)(t0 + 64) * DKH);
      vp1 = *(const u16x8*)(vg1 + (t0 + 64));
      vp2 = *(const u16x8*)(vg2 + (t0 + 64));
    }

    // em (value-domain mask), vectorized u16x4 at permuted t offsets
    u16x4 emA4[4], emB4[4];
#pragma unroll
    for (int j = 0; j < 4; ++j) {
      int f = t0 + ((j >> 1) << 5) + ((j & 1) << 2) + quad * 8;
      emA4[j] = *(const u16x4*)(emA + f);
      emB4[j] = *(const u16x4*)(emB + f);
    }

    // ---- swapped QK^T: C = K . Q^T -> lane holds P^T[t][q=col] ----
    f32x4 CA[4], CB[4];
#pragma unroll
    for (int j = 0; j < 4; ++j) {
      union { u16x8 u; bf16x8 v; } kb0, kb1;
      int row = j * 16 + col;
      kb0.u = *(const u16x8*)(Klds + row * KSTRIDE + quad * 8);
      kb1.u = *(const u16x8*)(Klds + row * KSTRIDE + 32 + quad * 8);
      f32x4 z = {};
      CA[j] = mfma_bf16(kb1.v, qA1, mfma_bf16(kb0.v, qA0, z));
      CB[j] = mfma_bf16(kb1.v, qB1, mfma_bf16(kb0.v, qB0, z));
    }

    // ---- softmax numerators: p = exp2(C)*em; pack straight into B-frags ----
    unsigned int PA[8], PB[8];
#pragma unroll
    for (int j = 0; j < 4; ++j) {
      float a0 = exp2_fast(CA[j][0]) * bf16u_f32(emA4[j][0]);
      float a1 = exp2_fast(CA[j][1]) * bf16u_f32(emA4[j][1]);
      float a2 = exp2_fast(CA[j][2]) * bf16u_f32(emA4[j][2]);
      float a3 = exp2_fast(CA[j][3]) * bf16u_f32(emA4[j][3]);
      lsumA += (a0 + a1) + (a2 + a3);
      PA[j * 2] = cvtpk(a0, a1);
      PA[j * 2 + 1] = cvtpk(a2, a3);
      float b0 = exp2_fast(CB[j][0]) * bf16u_f32(emB4[j][0]);
      float b1 = exp2_fast(CB[j][1]) * bf16u_f32(emB4[j][1]);
      float b2 = exp2_fast(CB[j][2]) * bf16u_f32(emB4[j][2]);
      float b3 = exp2_fast(CB[j][3]) * bf16u_f32(emB4[j][3]);
      lsumB += (b0 + b1) + (b2 + b3);
      PB[j * 2] = cvtpk(b0, b1);
      PB[j * 2 + 1] = cvtpk(b2, b3);
    }
    union { unsigned int u32[4]; bf16x8 v; } bA0, bA1, bB0, bB1;
#pragma unroll
    for (int i = 0; i < 4; ++i) {
      bA0.u32[i] = PA[i]; bA1.u32[i] = PA[4 + i];
      bB0.u32[i] = PB[i]; bB1.u32[i] = PB[4 + i];
    }

    // ---- PV: X^T = V^T . P^T (V frags shared by both q-sets) ----
#pragma unroll
    for (int ni = 0; ni < 4; ++ni) {
      union { u16x8 u; bf16x8 v; } vb0, vb1;
      int row = ni * 16 + col;
      vb0.u = *(const u16x8*)(Vlds + row * KSTRIDE + quad * 8);
      vb1.u = *(const u16x8*)(Vlds + row * KSTRIDE + 32 + quad * 8);
      xA[ni] = mfma_bf16(vb1.v, bA1.v, mfma_bf16(vb0.v, bA0.v, xA[ni]));
      xB[ni] = mfma_bf16(vb1.v, bB1.v, mfma_bf16(vb0.v, bB0.v, xB[ni]));
    }
    __syncthreads();
  }

  // denominators: sum over quads (lanes col, col+16, col+32, col+48)
  lsumA += __shfl_xor(lsumA, 16, 64); lsumA += __shfl_xor(lsumA, 32, 64);
  lsumB += __shfl_xor(lsumB, 16, 64); lsumB += __shfl_xor(lsumB, 32, 64);
  float rlA = 1.0f / lsumA, rlB = 1.0f / lsumB;

  // X^T[d = ni*16+quad*4+r][q = sX+col] -> x_ws[bh][q][d], 8B stores
  unsigned short* xo = (unsigned short*)x_ws;
#pragma unroll
  for (int ni = 0; ni < 4; ++ni) {
    uint2 wa, wb;
    wa.x = cvtpk(xA[ni][0] * rlA, xA[ni][1] * rlA);
    wa.y = cvtpk(xA[ni][2] * rlA, xA[ni][3] * rlA);
    wb.x = cvtpk(xB[ni][0] * rlB, xB[ni][1] * rlB);
    wb.y = cvtpk(xB[ni][2] * rlB, xB[ni][3] * rlB);
    *(uint2*)(xo + ((size_t)bh * S_LEN + sA + col) * DKH + ni * 16 + quad * 4) = wa;
    *(uint2*)(xo + ((size_t)bh * S_LEN + sB + col) * DKH + ni * 16 + quad * 4) = wb;
  }
  if (quad == 0) {
    rl_ws[(size_t)bh * S_LEN + sA + col] = rlA;
    rl_ws[(size_t)bh * S_LEN + sB + col] = rlB;
  }
}

// ---------------- kernel 4: attn = mean_h softmax (dbuf LDS K, 8 waves) ----
// grid (S/128=16, B, S/128=16) = 512 blocks = 2/CU; 512 thr = 8 waves.
// Block owns 128 q x 128 t. Per head: K tile (128x128B) double-buffered via
// global_load_lds with SOURCE-side XOR chunk swizzle (linear LDS dest, read
// with same XOR -> conflict-free). One barrier per head. q/rl prefetched.
__global__ __launch_bounds__(512) void attn_kernel(
    const bf16_t* __restrict__ emb,
    const bf16_t* __restrict__ q_ws, const bf16_t* __restrict__ k_ws,
    const float* __restrict__ rl_ws,
    float* __restrict__ attn_out) {
  int tid = threadIdx.x;
  int w = tid >> 6, lane = tid & 63, quad = lane >> 4, col = lane & 15;
  int b = blockIdx.y;
  int s0 = blockIdx.x * 128 + w * 16;
  int t_base = blockIdx.z * 128;

  __shared__ __align__(16) unsigned short Klds[2][128 * 64];  // 32 KB dbuf

  // em (h-independent) held in registers for the whole block
  const unsigned short* emrow = (const unsigned short*)emb +
      (size_t)b * S_LEN * S_LEN + (size_t)(s0 + quad * 4) * S_LEN + t_base;
  float emf[8][4];
#pragma unroll
  for (int j = 0; j < 8; ++j)
#pragma unroll
    for (int r = 0; r < 4; ++r)
      emf[j][r] = bf16u_f32(emrow[r * S_LEN + j * 16 + col]);

  // staging: thread covers lds shorts tid*8 and 4096+tid*8 (linear dest);
  // global source chunk XOR-swizzled: LDS[row][c] = K[t_base+row][c^(row&7)]
  int srow = tid >> 3;                               // 0..63 (and +64)
  int csw = ((tid & 7) ^ (srow & 7)) * 8;            // src chunk elems
  const bf16_t* kh0 = k_ws + (size_t)(b * NH) * S_LEN * DKH;
  const bf16_t* ks1 = kh0 + (size_t)(t_base + srow) * DKH + csw;
  const bf16_t* ks2 = kh0 + (size_t)(t_base + 64 + srow) * DKH + csw;

  const bf16_t* qp0 = q_ws + (size_t)(b * NH) * S_LEN * DKH + (size_t)(s0 + col) * DKH;
  const float* rlp = rl_ws + (size_t)(b * NH) * S_LEN + s0 + quad * 4;

  f32x4 acc[8] = {};

  // prologue: stage h=0 into buf0; q/rl for h=0
  gload16(ks1, &Klds[0][0] + tid * 8);
  gload16(ks2, &Klds[0][0] + 4096 + tid * 8);
  bf16x8 qf0c = *(const bf16x8*)(qp0 + quad * 8);
  bf16x8 qf1c = *(const bf16x8*)(qp0 + 32 + quad * 8);
  float rlc[4];
#pragma unroll
  for (int r = 0; r < 4; ++r) rlc[r] = rlp[r];
  __syncthreads();

  int cur = 0;
  for (int h = 0; h < NH; ++h) {
    bf16x8 qf0n = qf0c, qf1n = qf1c;
    float rln[4] = {rlc[0], rlc[1], rlc[2], rlc[3]};
    if (h + 1 < NH) {
      size_t off = (size_t)(h + 1) * S_LEN * DKH;
      unsigned short* dn = &Klds[cur ^ 1][0];
      gload16(ks1 + off, dn + tid * 8);
      gload16(ks2 + off, dn + 4096 + tid * 8);
      qf0n = *(const bf16x8*)(qp0 + off + quad * 8);
      qf1n = *(const bf16x8*)(qp0 + off + 32 + quad * 8);
      const float* rlh = rlp + (size_t)(h + 1) * S_LEN;
#pragma unroll
      for (int r = 0; r < 4; ++r) rln[r] = rlh[r];
    }

    const unsigned short* kb = &Klds[cur][0];
#pragma unroll
    for (int j = 0; j < 8; ++j) {
      int row = j * 16 + col;
      int rsw = row & 7;
      union { u16x8 u; bf16x8 v; } kb0, kb1;
      kb0.u = *(const u16x8*)(kb + row * 64 + ((quad ^ rsw) << 3));
      kb1.u = *(const u16x8*)(kb + row * 64 + (((quad + 4) ^ rsw) << 3));
      f32x4 z = {};
      f32x4 C = mfma_bf16(qf1c, kb1.v, mfma_bf16(qf0c, kb0.v, z));
#pragma unroll
      for (int r = 0; r < 4; ++r)
        acc[j][r] = fmaf(exp2_fast(C[r]), rlc[r], acc[j][r]);
    }
    __syncthreads();
    cur ^= 1;
    qf0c = qf0n; qf1c = qf1n;
#pragma unroll
    for (int r = 0; r < 4; ++r) rlc[r] = rln[r];
  }

#pragma unroll
  for (int j = 0; j < 8; ++j)
#pragma unroll
    for (int r = 0; r < 4; ++r)
      attn_out[((size_t)b * S_LEN + s0 + quad * 4 + r) * S_LEN + t_base + j * 16 + col] =
          acc[j][r] * emf[j][r] * (1.0f / NH);
}

// ---------------- kernel 5: out projection (m97-structure GEMM, f32 out) ---
// grid (M/128=32, N/128=8); 256 thr = 4 waves (2x2), wave owns 64x64.
__global__ __launch_bounds__(256) void outproj_kernel(
    const bf16_t* __restrict__ x_ws, const bf16_t* __restrict__ Wob,
    const float* __restrict__ bo, float* __restrict__ out) {
  __shared__ __align__(16) unsigned short Alds[128 * 32];  // 8 KB
  __shared__ __align__(16) unsigned short Blds[128 * 32];  // 8 KB

  int tid = threadIdx.x;
  int wv = tid >> 6, lane = tid & 63, quad = lane >> 4, col = lane & 15;
  int wr = wv >> 1, wc = wv & 1;
  int rowbase = blockIdx.x * 128;
  int colbase = blockIdx.y * 128;

  int srow = tid >> 2;           // 0..63
  int sk8 = (tid & 3) * 8;       // k-elem offset of the chunk
  int r0 = rowbase + srow;       // A rows for staging (and r0+64)
  int s0a = r0 >> 1, b0a = r0 & 1;
  int r1 = r0 + 64;
  int s1a = r1 >> 1, b1a = r1 & 1;
  const bf16_t* gb0 = Wob + (size_t)(colbase + srow) * DMODEL + sk8;
  unsigned short* la0 = Alds + tid * 8;
  unsigned short* lb0 = Blds + tid * 8;

  f32x4 acc[4][4] = {};

  for (int k0 = 0; k0 < DMODEL; k0 += 32) {
    int h = k0 >> 6, dk = (k0 & 63) + sk8;  // head-scattered A source
    gload16(x_ws + ((size_t)(b0a * NH + h) * S_LEN + s0a) * DKH + dk, la0);
    gload16(x_ws + ((size_t)(b1a * NH + h) * S_LEN + s1a) * DKH + dk, la0 + 2048);
    gload16(gb0 + k0, lb0);
    gload16(gb0 + 64 * DMODEL + k0, lb0 + 2048);
    __syncthreads();

    union { u16x8 u; bf16x8 v; } af[4], bfr[4];
#pragma unroll
    for (int mi = 0; mi < 4; ++mi)
      af[mi].u = *(const u16x8*)(Alds + (wr * 64 + mi * 16 + col) * 32 + quad * 8);
#pragma unroll
    for (int ni = 0; ni < 4; ++ni)
      bfr[ni].u = *(const u16x8*)(Blds + (wc * 64 + ni * 16 + col) * 32 + quad * 8);
#pragma unroll
    for (int mi = 0; mi < 4; ++mi)
#pragma unroll
      for (int ni = 0; ni < 4; ++ni)
        acc[mi][ni] = mfma_bf16(af[mi].v, bfr[ni].v, acc[mi][ni]);
    __syncthreads();
  }

  float biasv[4];
#pragma unroll
  for (int ni = 0; ni < 4; ++ni)
    biasv[ni] = bo[colbase + wc * 64 + ni * 16 + col];

#pragma unroll
  for (int mi = 0; mi < 4; ++mi)
#pragma unroll
    for (int ni = 0; ni < 4; ++ni)
#pragma unroll
      for (int r = 0; r < 4; ++r) {
        int grow = rowbase + wr * 64 + mi * 16 + quad * 4 + r;  // == s*B + b
        int gcol = colbase + wc * 64 + ni * 16 + col;
        out[(size_t)grow * DMODEL + gcol] = acc[mi][ni][r] + biasv[ni];
      }
}

// ---------------- launch ----------------------------------------------------
extern "C" void kernel_launch(void* const* d_in, const int* in_sizes, int n_in,
                              void* d_out, int out_size, void* d_ws, size_t ws_size,
                              hipStream_t stream) {
  const float* query = (const float*)d_in[0];
  const float* key_  = (const float*)d_in[1];
  const float* value = (const float*)d_in[2];
  const float* mask  = (const float*)d_in[3];
  const float* Wq = (const float*)d_in[4];
  const float* bq = (const float*)d_in[5];
  const float* Wk = (const float*)d_in[6];
  const float* bk = (const float*)d_in[7];
  const float* Wv = (const float*)d_in[8];
  const float* bv = (const float*)d_in[9];
  const float* Wo = (const float*)d_in[10];
  const float* bo = (const float*)d_in[11];

  char* ws = (char*)d_ws;
  bf16_t* q_ws  = (bf16_t*)(ws + 0);          //  8 MB (B,H,S,DK), pre-scaled
  bf16_t* k_ws  = (bf16_t*)(ws + 8388608);    //  8 MB (B,H,S,DK)
  bf16_t* vT_ws = (bf16_t*)(ws + 16777216);   //  8 MB (B,H,DK,S)
  bf16_t* x_ws  = (bf16_t*)(ws + 25165824);   //  8 MB; aliases Xq-bf16 during proj
  float*  rl_ws = (float*)(ws + 33554432);    //  256 KB (B,H,S)
  bf16_t* Wqb = (bf16_t*)(ws + 33816576);     //  2 MB each
  bf16_t* Wkb = (bf16_t*)(ws + 35913728);
  bf16_t* Wvb = (bf16_t*)(ws + 38010880);
  bf16_t* Wob = (bf16_t*)(ws + 40108032);
  bf16_t* Xq_b = x_ws;                        //  8 MB (consumed by proj)
  bf16_t* Xk_b = (bf16_t*)(ws + 42205184);    //  8 MB (consumed by proj)
  bf16_t* Xv_b = (bf16_t*)(ws + 50593792);    //  8 MB (consumed by proj)
  bf16_t* emb  = (bf16_t*)(ws + 42205184);    // 16.8 MB; overwrites Xk_b/Xv_b AFTER proj

  float* outp  = (float*)d_out;                              // (S,B,D) f32
  float* attnp = outp + (size_t)S_LEN * BATCH * DMODEL;      // (B,S,S) f32

  cvt_w_kernel<<<dim3(1024, 4), 256, 0, stream>>>(Wq, Wk, Wv, Wo, Wqb, Wkb, Wvb, Wob);
  cvt_x_kernel<<<dim3(4096, 3), 256, 0, stream>>>(query, key_, value, Xq_b, Xk_b, Xv_b);
  proj_kernel<<<dim3(32, 8, 3), 256, 0, stream>>>(Xq_b, Xk_b, Xv_b,
                                                  Wqb, Wkb, Wvb, bq, bk, bv,
                                                  q_ws, k_ws, vT_ws);
  cvt_mask_kernel<<<dim3(8192), 256, 0, stream>>>(mask, emb);
  flash_kernel<<<dim3(512), 256, 0, stream>>>(emb, q_ws, k_ws, vT_ws, x_ws, rl_ws);
  attn_kernel<<<dim3(16, 2, 16), 512, 0, stream>>>(emb, q_ws, k_ws, rl_ws, attnp);
  outproj_kernel<<<dim3(32, 8), 256, 0, stream>>>(x_ws, Wob, bo, outp);
}